// Round 1
// baseline (1146.898 us; speedup 1.0000x reference)
//
#include <hip/hip_runtime.h>

#define H 128
#define GEMM_ROWS 64
#define KT 64            // k-tile for GEMM (keeps LDS <= 64KB)
#define HS_PITCH 68      // padded pitch for Hs tile (breaks 4-way bank conflict)

// ---------------- degree histogram ----------------
__global__ __launch_bounds__(256) void k_deg(const int* __restrict__ dst,
                                             int* __restrict__ cnt, int E) {
  int e = blockIdx.x * 256 + threadIdx.x;
  if (e < E) atomicAdd(&cnt[dst[e]], 1);
}

// ---------------- exclusive scan (single block) + dinv ----------------
__global__ __launch_bounds__(1024) void k_scan(const int* __restrict__ cnt,
                                               int* __restrict__ roff,
                                               int* __restrict__ cursor,
                                               float* __restrict__ dinv, int n) {
  __shared__ int sums[1024];
  int tid = threadIdx.x;
  int carry = 0;
  const int CH = 16;
  for (int base = 0; base < n; base += 1024 * CH) {
    int i0 = base + tid * CH;
    int local[CH];
    int s = 0;
#pragma unroll
    for (int j = 0; j < CH; j++) {
      int i = i0 + j;
      int v = (i < n) ? cnt[i] : 0;
      local[j] = s;
      s += v;
      if (i < n) dinv[i] = rsqrtf((float)v + 1.0f);
    }
    sums[tid] = s;
    __syncthreads();
    for (int off = 1; off < 1024; off <<= 1) {
      int t = (tid >= off) ? sums[tid - off] : 0;
      __syncthreads();
      sums[tid] += t;
      __syncthreads();
    }
    int excl = carry + sums[tid] - s;
#pragma unroll
    for (int j = 0; j < CH; j++) {
      int i = i0 + j;
      if (i < n) {
        int v = excl + local[j];
        roff[i] = v;
        cursor[i] = v;
      }
    }
    carry += sums[1023];
    __syncthreads();
  }
  if (tid == 0) roff[n] = carry;
}

// ---------------- CSR fill ----------------
__global__ __launch_bounds__(256) void k_fill(const int* __restrict__ src,
                                              const int* __restrict__ dst,
                                              int* __restrict__ cursor,
                                              int* __restrict__ csr, int E) {
  int e = blockIdx.x * 256 + threadIdx.x;
  if (e < E) {
    int d = dst[e];
    int pos = atomicAdd(&cursor[d], 1);
    csr[pos] = src[e];
  }
}

// ---------------- fp32 GEMM: out = (relu? relu(in) : in) @ W ----------------
// block 256 threads, 64 rows x 128 cols per block, k tiled at 64
__global__ __launch_bounds__(256) void k_gemm(const float* __restrict__ in,
                                              const float* __restrict__ Wm,
                                              float* __restrict__ out, int n, int relu) {
  __shared__ float Ws[KT * H];             // 32 KB: W[kt..kt+63][0..127]
  __shared__ float Hs[GEMM_ROWS * HS_PITCH]; // ~17 KB: rows x k-tile (padded)
  int tid = threadIdx.x;
  int row0 = blockIdx.x * GEMM_ROWS;

  int c8 = (tid & 15) * 8;
  int r4 = (tid >> 4) * 4;
  float acc[4][8];
#pragma unroll
  for (int r = 0; r < 4; r++)
#pragma unroll
    for (int c = 0; c < 8; c++) acc[r][c] = 0.f;

  const float4* in4 = (const float4*)in;
  const float4* W4 = (const float4*)Wm;

  for (int kt = 0; kt < H; kt += KT) {
    // stage W k-tile: KT*H floats = 2048 float4, 8 per thread
#pragma unroll
    for (int i = 0; i < (KT * H / 4) / 256; i++) {
      int idx = tid + 256 * i;
      ((float4*)Ws)[idx] = W4[(kt * H / 4) + idx];
    }
    // stage H tile: 64 rows x KT cols = 1024 float4, 4 per thread
#pragma unroll
    for (int i = 0; i < (GEMM_ROWS * KT / 4) / 256; i++) {
      int idx = tid + 256 * i;
      int r = idx >> 4;          // KT/4 = 16 float4 per row
      int c4 = idx & 15;
      int gr = row0 + r;
      float4 v = make_float4(0.f, 0.f, 0.f, 0.f);
      if (gr < n) {
        v = in4[gr * (H / 4) + (kt / 4) + c4];
        if (relu) {
          v.x = fmaxf(v.x, 0.f); v.y = fmaxf(v.y, 0.f);
          v.z = fmaxf(v.z, 0.f); v.w = fmaxf(v.w, 0.f);
        }
      }
      *(float4*)&Hs[r * HS_PITCH + c4 * 4] = v;
    }
    __syncthreads();

    for (int k0 = 0; k0 < KT; k0 += 4) {
      float4 hv[4];
#pragma unroll
      for (int r = 0; r < 4; r++)
        hv[r] = *(const float4*)&Hs[(r4 + r) * HS_PITCH + k0];
#pragma unroll
      for (int kk = 0; kk < 4; kk++) {
        float4 wa = *(const float4*)&Ws[(k0 + kk) * H + c8];
        float4 wb = *(const float4*)&Ws[(k0 + kk) * H + c8 + 4];
#pragma unroll
        for (int r = 0; r < 4; r++) {
          float hk = ((const float*)&hv[r])[kk];
          acc[r][0] += hk * wa.x; acc[r][1] += hk * wa.y;
          acc[r][2] += hk * wa.z; acc[r][3] += hk * wa.w;
          acc[r][4] += hk * wb.x; acc[r][5] += hk * wb.y;
          acc[r][6] += hk * wb.z; acc[r][7] += hk * wb.w;
        }
      }
    }
    __syncthreads();
  }

#pragma unroll
  for (int r = 0; r < 4; r++) {
    int gr = row0 + r4 + r;
    if (gr < n) {
      float4 o0 = make_float4(acc[r][0], acc[r][1], acc[r][2], acc[r][3]);
      float4 o1 = make_float4(acc[r][4], acc[r][5], acc[r][6], acc[r][7]);
      *(float4*)&out[gr * H + c8] = o0;
      *(float4*)&out[gr * H + c8 + 4] = o1;
    }
  }
}

// ---------------- aggregation: one wave per node ----------------
// out[i,:] = b + x[i,:] + dinv[i]^2 * h[i,:] + sum_e dinv[src]*dinv[i]*h[src,:]
__global__ __launch_bounds__(256) void k_agg(const float* __restrict__ h,
                                             const int* __restrict__ csr,
                                             const int* __restrict__ roff,
                                             const float* __restrict__ dinv,
                                             const float* __restrict__ bias,
                                             const float* __restrict__ x,
                                             float* __restrict__ out, int n) {
  int wave = threadIdx.x >> 6;
  int lane = threadIdx.x & 63;
  int node = blockIdx.x * 4 + wave;
  if (node >= n) return;

  const float2* h2 = (const float2*)h;
  float di = dinv[node];
  float2 self = h2[(size_t)node * 64 + lane];
  float2 xv = ((const float2*)x)[(size_t)node * 64 + lane];
  float2 bv = ((const float2*)bias)[lane];
  float acc0 = bv.x + xv.x + di * di * self.x;
  float acc1 = bv.y + xv.y + di * di * self.y;

  int e0 = roff[node], e1 = roff[node + 1];
  for (int e = e0; e < e1; e++) {
    int s = csr[e];
    float coef = di * dinv[s];
    float2 hv = h2[(size_t)s * 64 + lane];
    acc0 += coef * hv.x;
    acc1 += coef * hv.y;
  }
  ((float2*)out)[(size_t)node * 64 + lane] = make_float2(acc0, acc1);
}

extern "C" void kernel_launch(void* const* d_in, const int* in_sizes, int n_in,
                              void* d_out, int out_size, void* d_ws, size_t ws_size,
                              hipStream_t stream) {
  const float* x = (const float*)d_in[0];
  const int* src = (const int*)d_in[1];
  const int* dst = (const int*)d_in[2];
  const float* W1 = (const float*)d_in[3];
  const float* b1 = (const float*)d_in[4];
  const float* W2 = (const float*)d_in[5];
  const float* b2 = (const float*)d_in[6];
  int N = in_sizes[0] / H;
  int E = in_sizes[1];
  float* out = (float*)d_out;

  char* p = (char*)d_ws;
  auto alloc = [&](size_t bytes) {
    char* q = p;
    p += (bytes + 255) & ~(size_t)255;
    return q;
  };
  int* cnt = (int*)alloc((size_t)N * 4);
  int* roff = (int*)alloc((size_t)(N + 1) * 4);
  int* cursor = (int*)alloc((size_t)N * 4);
  float* dinv = (float*)alloc((size_t)N * 4);
  int* csr = (int*)alloc((size_t)E * 4);
  float* htmp = (float*)alloc((size_t)N * H * 4);
  float* ybuf = (float*)alloc((size_t)N * H * 4);

  hipMemsetAsync(cnt, 0, (size_t)N * 4, stream);
  k_deg<<<(E + 255) / 256, 256, 0, stream>>>(dst, cnt, E);
  k_scan<<<1, 1024, 0, stream>>>(cnt, roff, cursor, dinv, N);
  k_fill<<<(E + 255) / 256, 256, 0, stream>>>(src, dst, cursor, csr, E);

  int gb = (N + GEMM_ROWS - 1) / GEMM_ROWS;
  int ab = (N + 3) / 4;

  // layer 1: W1,b1, input x (no relu)
  k_gemm<<<gb, 256, 0, stream>>>(x, W1, htmp, N, 0);
  k_agg<<<ab, 256, 0, stream>>>(htmp, csr, roff, dinv, b1, x, ybuf, N);
  // layer 2: W2,b2, input relu(y1)
  k_gemm<<<gb, 256, 0, stream>>>(ybuf, W2, htmp, N, 1);
  k_agg<<<ab, 256, 0, stream>>>(htmp, csr, roff, dinv, b2, x, ybuf, N);
  // layer 3: W2,b2, input relu(y2)
  k_gemm<<<gb, 256, 0, stream>>>(ybuf, W2, htmp, N, 1);
  k_agg<<<ab, 256, 0, stream>>>(htmp, csr, roff, dinv, b2, x, out, N);
}

// Round 2
// 842.607 us; speedup vs baseline: 1.3611x; 1.3611x over previous
//
#include <hip/hip_runtime.h>

#define H 128
#define GEMM_ROWS 64
#define KT 64            // k-tile for GEMM (keeps LDS <= 64KB)
#define HS_PITCH 68      // padded pitch for Hs tile (breaks 4-way bank conflict)
#define SCAN_BLK 1024    // elements per scan block (256 threads x 4)

// ---------------- degree histogram ----------------
__global__ __launch_bounds__(256) void k_deg(const int* __restrict__ dst,
                                             int* __restrict__ cnt, int E) {
  int e = blockIdx.x * 256 + threadIdx.x;
  if (e < E) atomicAdd(&cnt[dst[e]], 1);
}

// ---------------- hierarchical scan: stage 1 (per-block sums) ----------------
__global__ __launch_bounds__(256) void k_scan1(const int* __restrict__ cnt,
                                               int* __restrict__ bsum, int n) {
  __shared__ int red[256];
  int tid = threadIdx.x;
  int i0 = blockIdx.x * SCAN_BLK + tid * 4;
  int s = 0;
#pragma unroll
  for (int j = 0; j < 4; j++) {
    int i = i0 + j;
    if (i < n) s += cnt[i];
  }
  red[tid] = s;
  __syncthreads();
  for (int off = 128; off > 0; off >>= 1) {
    if (tid < off) red[tid] += red[tid + off];
    __syncthreads();
  }
  if (tid == 0) bsum[blockIdx.x] = red[0];
}

// ---------------- stage 2: exclusive scan of block sums (1 block) ----------------
__global__ __launch_bounds__(1024) void k_scan2(const int* __restrict__ bsum,
                                                int* __restrict__ boff,
                                                int* __restrict__ roff,
                                                int nb, int n) {
  __shared__ int sums[1024];
  int tid = threadIdx.x;
  int v = (tid < nb) ? bsum[tid] : 0;
  sums[tid] = v;
  __syncthreads();
  for (int off = 1; off < 1024; off <<= 1) {
    int t = (tid >= off) ? sums[tid - off] : 0;
    __syncthreads();
    sums[tid] += t;
    __syncthreads();
  }
  if (tid < nb) boff[tid] = sums[tid] - v;
  if (tid == 1023) roff[n] = sums[1023];
}

// ---------------- stage 3: per-block rescan + write roff/cursor/dinv ----------------
__global__ __launch_bounds__(256) void k_scan3(const int* __restrict__ cnt,
                                               const int* __restrict__ boff,
                                               int* __restrict__ roff,
                                               int* __restrict__ cursor,
                                               float* __restrict__ dinv, int n) {
  __shared__ int sums[256];
  int tid = threadIdx.x;
  int i0 = blockIdx.x * SCAN_BLK + tid * 4;
  int local[4];
  int s = 0;
#pragma unroll
  for (int j = 0; j < 4; j++) {
    int i = i0 + j;
    int v = (i < n) ? cnt[i] : 0;
    local[j] = s;
    s += v;
    if (i < n) dinv[i] = rsqrtf((float)v + 1.0f);
  }
  sums[tid] = s;
  __syncthreads();
  for (int off = 1; off < 256; off <<= 1) {
    int t = (tid >= off) ? sums[tid - off] : 0;
    __syncthreads();
    sums[tid] += t;
    __syncthreads();
  }
  int base = boff[blockIdx.x] + sums[tid] - s;
#pragma unroll
  for (int j = 0; j < 4; j++) {
    int i = i0 + j;
    if (i < n) {
      int v = base + local[j];
      roff[i] = v;
      cursor[i] = v;
    }
  }
}

// ---------------- CSR fill ----------------
__global__ __launch_bounds__(256) void k_fill(const int* __restrict__ src,
                                              const int* __restrict__ dst,
                                              int* __restrict__ cursor,
                                              int* __restrict__ csr, int E) {
  int e = blockIdx.x * 256 + threadIdx.x;
  if (e < E) {
    int d = dst[e];
    int pos = atomicAdd(&cursor[d], 1);
    csr[pos] = src[e];
  }
}

// ---------------- fp32 GEMM: out = (relu? relu(in) : in) @ W ----------------
__global__ __launch_bounds__(256) void k_gemm(const float* __restrict__ in,
                                              const float* __restrict__ Wm,
                                              float* __restrict__ out, int n, int relu) {
  __shared__ float Ws[KT * H];
  __shared__ float Hs[GEMM_ROWS * HS_PITCH];
  int tid = threadIdx.x;
  int row0 = blockIdx.x * GEMM_ROWS;

  int c8 = (tid & 15) * 8;
  int r4 = (tid >> 4) * 4;
  float acc[4][8];
#pragma unroll
  for (int r = 0; r < 4; r++)
#pragma unroll
    for (int c = 0; c < 8; c++) acc[r][c] = 0.f;

  const float4* in4 = (const float4*)in;
  const float4* W4 = (const float4*)Wm;

  for (int kt = 0; kt < H; kt += KT) {
#pragma unroll
    for (int i = 0; i < (KT * H / 4) / 256; i++) {
      int idx = tid + 256 * i;
      ((float4*)Ws)[idx] = W4[(kt * H / 4) + idx];
    }
#pragma unroll
    for (int i = 0; i < (GEMM_ROWS * KT / 4) / 256; i++) {
      int idx = tid + 256 * i;
      int r = idx >> 4;
      int c4 = idx & 15;
      int gr = row0 + r;
      float4 v = make_float4(0.f, 0.f, 0.f, 0.f);
      if (gr < n) {
        v = in4[gr * (H / 4) + (kt / 4) + c4];
        if (relu) {
          v.x = fmaxf(v.x, 0.f); v.y = fmaxf(v.y, 0.f);
          v.z = fmaxf(v.z, 0.f); v.w = fmaxf(v.w, 0.f);
        }
      }
      *(float4*)&Hs[r * HS_PITCH + c4 * 4] = v;
    }
    __syncthreads();

    for (int k0 = 0; k0 < KT; k0 += 4) {
      float4 hv[4];
#pragma unroll
      for (int r = 0; r < 4; r++)
        hv[r] = *(const float4*)&Hs[(r4 + r) * HS_PITCH + k0];
#pragma unroll
      for (int kk = 0; kk < 4; kk++) {
        float4 wa = *(const float4*)&Ws[(k0 + kk) * H + c8];
        float4 wb = *(const float4*)&Ws[(k0 + kk) * H + c8 + 4];
#pragma unroll
        for (int r = 0; r < 4; r++) {
          float hk = ((const float*)&hv[r])[kk];
          acc[r][0] += hk * wa.x; acc[r][1] += hk * wa.y;
          acc[r][2] += hk * wa.z; acc[r][3] += hk * wa.w;
          acc[r][4] += hk * wb.x; acc[r][5] += hk * wb.y;
          acc[r][6] += hk * wb.z; acc[r][7] += hk * wb.w;
        }
      }
    }
    __syncthreads();
  }

#pragma unroll
  for (int r = 0; r < 4; r++) {
    int gr = row0 + r4 + r;
    if (gr < n) {
      float4 o0 = make_float4(acc[r][0], acc[r][1], acc[r][2], acc[r][3]);
      float4 o1 = make_float4(acc[r][4], acc[r][5], acc[r][6], acc[r][7]);
      *(float4*)&out[gr * H + c8] = o0;
      *(float4*)&out[gr * H + c8 + 4] = o1;
    }
  }
}

// ---------------- aggregation: one wave per node, 4x unrolled gather ----------------
// out[i,:] = b + x[i,:] + dinv[i]^2 * h[i,:] + sum_e dinv[src]*dinv[i]*h[src,:]
__global__ __launch_bounds__(256) void k_agg(const float* __restrict__ h,
                                             const int* __restrict__ csr,
                                             const int* __restrict__ roff,
                                             const float* __restrict__ dinv,
                                             const float* __restrict__ bias,
                                             const float* __restrict__ x,
                                             float* __restrict__ out, int n) {
  int wave = threadIdx.x >> 6;
  int lane = threadIdx.x & 63;
  int node = blockIdx.x * 4 + wave;
  if (node >= n) return;

  const float2* h2 = (const float2*)h;
  float di = dinv[node];
  float2 self = h2[(size_t)node * 64 + lane];
  float2 xv = ((const float2*)x)[(size_t)node * 64 + lane];
  float2 bv = ((const float2*)bias)[lane];
  float acc0 = bv.x + xv.x + di * di * self.x;
  float acc1 = bv.y + xv.y + di * di * self.y;

  int e0 = roff[node], e1 = roff[node + 1];
  int e = e0;
  for (; e + 4 <= e1; e += 4) {
    int s0 = csr[e], s1 = csr[e + 1], s2 = csr[e + 2], s3 = csr[e + 3];
    float c0 = di * dinv[s0], c1 = di * dinv[s1];
    float c2 = di * dinv[s2], c3 = di * dinv[s3];
    float2 v0 = h2[(size_t)s0 * 64 + lane];
    float2 v1 = h2[(size_t)s1 * 64 + lane];
    float2 v2 = h2[(size_t)s2 * 64 + lane];
    float2 v3 = h2[(size_t)s3 * 64 + lane];
    acc0 += c0 * v0.x + c1 * v1.x;
    acc1 += c0 * v0.y + c1 * v1.y;
    acc0 += c2 * v2.x + c3 * v3.x;
    acc1 += c2 * v2.y + c3 * v3.y;
  }
  for (; e < e1; e++) {
    int s = csr[e];
    float coef = di * dinv[s];
    float2 hv = h2[(size_t)s * 64 + lane];
    acc0 += coef * hv.x;
    acc1 += coef * hv.y;
  }
  ((float2*)out)[(size_t)node * 64 + lane] = make_float2(acc0, acc1);
}

extern "C" void kernel_launch(void* const* d_in, const int* in_sizes, int n_in,
                              void* d_out, int out_size, void* d_ws, size_t ws_size,
                              hipStream_t stream) {
  const float* x = (const float*)d_in[0];
  const int* src = (const int*)d_in[1];
  const int* dst = (const int*)d_in[2];
  const float* W1 = (const float*)d_in[3];
  const float* b1 = (const float*)d_in[4];
  const float* W2 = (const float*)d_in[5];
  const float* b2 = (const float*)d_in[6];
  int N = in_sizes[0] / H;
  int E = in_sizes[1];
  float* out = (float*)d_out;

  char* p = (char*)d_ws;
  auto alloc = [&](size_t bytes) {
    char* q = p;
    p += (bytes + 255) & ~(size_t)255;
    return q;
  };
  int* cnt = (int*)alloc((size_t)N * 4);
  int* roff = (int*)alloc((size_t)(N + 1) * 4);
  int* cursor = (int*)alloc((size_t)N * 4);
  float* dinv = (float*)alloc((size_t)N * 4);
  int* csr = (int*)alloc((size_t)E * 4);
  float* htmp = (float*)alloc((size_t)N * H * 4);
  float* ybuf = (float*)alloc((size_t)N * H * 4);
  int* bsum = (int*)alloc(1024 * 4);
  int* boff = (int*)alloc(1024 * 4);

  int nb = (N + SCAN_BLK - 1) / SCAN_BLK;  // 98 for N=100000 (must be <=1024)

  hipMemsetAsync(cnt, 0, (size_t)N * 4, stream);
  k_deg<<<(E + 255) / 256, 256, 0, stream>>>(dst, cnt, E);
  k_scan1<<<nb, 256, 0, stream>>>(cnt, bsum, N);
  k_scan2<<<1, 1024, 0, stream>>>(bsum, boff, roff, nb, N);
  k_scan3<<<nb, 256, 0, stream>>>(cnt, boff, roff, cursor, dinv, N);
  k_fill<<<(E + 255) / 256, 256, 0, stream>>>(src, dst, cursor, csr, E);

  int gb = (N + GEMM_ROWS - 1) / GEMM_ROWS;
  int ab = (N + 3) / 4;

  // layer 1: W1,b1, input x (no relu)
  k_gemm<<<gb, 256, 0, stream>>>(x, W1, htmp, N, 0);
  k_agg<<<ab, 256, 0, stream>>>(htmp, csr, roff, dinv, b1, x, ybuf, N);
  // layer 2: W2,b2, input relu(y1)
  k_gemm<<<gb, 256, 0, stream>>>(ybuf, W2, htmp, N, 1);
  k_agg<<<ab, 256, 0, stream>>>(htmp, csr, roff, dinv, b2, x, ybuf, N);
  // layer 3: W2,b2, input relu(y2)
  k_gemm<<<gb, 256, 0, stream>>>(ybuf, W2, htmp, N, 1);
  k_agg<<<ab, 256, 0, stream>>>(htmp, csr, roff, dinv, b2, x, out, N);
}

// Round 3
// 606.919 us; speedup vs baseline: 1.8897x; 1.3883x over previous
//
#include <hip/hip_runtime.h>

#define H 128
#define AP 136           // LDS row pitch in shorts (136*2=272B, 16B-aligned, spreads banks)
#define SCAN_BLK 1024

typedef __attribute__((ext_vector_type(8))) short short8;
typedef __attribute__((ext_vector_type(4))) float floatx4;

__device__ inline unsigned short f2b(float f) {   // fp32 -> bf16 RNE
  union { float f; unsigned u; } v; v.f = f;
  unsigned r = v.u + 0x7fffu + ((v.u >> 16) & 1u);
  return (unsigned short)(r >> 16);
}

// ---------------- degree histogram ----------------
__global__ __launch_bounds__(256) void k_deg(const int* __restrict__ dst,
                                             int* __restrict__ cnt, int E) {
  int e = blockIdx.x * 256 + threadIdx.x;
  if (e < E) atomicAdd(&cnt[dst[e]], 1);
}

// ---------------- hierarchical scan ----------------
__global__ __launch_bounds__(256) void k_scan1(const int* __restrict__ cnt,
                                               int* __restrict__ bsum, int n) {
  __shared__ int red[256];
  int tid = threadIdx.x;
  int i0 = blockIdx.x * SCAN_BLK + tid * 4;
  int s = 0;
#pragma unroll
  for (int j = 0; j < 4; j++) { int i = i0 + j; if (i < n) s += cnt[i]; }
  red[tid] = s;
  __syncthreads();
  for (int off = 128; off > 0; off >>= 1) {
    if (tid < off) red[tid] += red[tid + off];
    __syncthreads();
  }
  if (tid == 0) bsum[blockIdx.x] = red[0];
}

__global__ __launch_bounds__(1024) void k_scan2(const int* __restrict__ bsum,
                                                int* __restrict__ boff,
                                                int* __restrict__ roff,
                                                int nb, int n) {
  __shared__ int sums[1024];
  int tid = threadIdx.x;
  int v = (tid < nb) ? bsum[tid] : 0;
  sums[tid] = v;
  __syncthreads();
  for (int off = 1; off < 1024; off <<= 1) {
    int t = (tid >= off) ? sums[tid - off] : 0;
    __syncthreads();
    sums[tid] += t;
    __syncthreads();
  }
  if (tid < nb) boff[tid] = sums[tid] - v;
  if (tid == 1023) roff[n] = sums[1023];
}

__global__ __launch_bounds__(256) void k_scan3(const int* __restrict__ cnt,
                                               const int* __restrict__ boff,
                                               int* __restrict__ roff,
                                               int* __restrict__ cursor,
                                               float* __restrict__ dinv, int n) {
  __shared__ int sums[256];
  int tid = threadIdx.x;
  int i0 = blockIdx.x * SCAN_BLK + tid * 4;
  int local[4];
  int s = 0;
#pragma unroll
  for (int j = 0; j < 4; j++) {
    int i = i0 + j;
    int v = (i < n) ? cnt[i] : 0;
    local[j] = s;
    s += v;
    if (i < n) dinv[i] = rsqrtf((float)v + 1.0f);
  }
  sums[tid] = s;
  __syncthreads();
  for (int off = 1; off < 256; off <<= 1) {
    int t = (tid >= off) ? sums[tid - off] : 0;
    __syncthreads();
    sums[tid] += t;
    __syncthreads();
  }
  int base = boff[blockIdx.x] + sums[tid] - s;
#pragma unroll
  for (int j = 0; j < 4; j++) {
    int i = i0 + j;
    if (i < n) { int v = base + local[j]; roff[i] = v; cursor[i] = v; }
  }
}

// ---------------- CSR fill ----------------
__global__ __launch_bounds__(256) void k_fill(const int* __restrict__ src,
                                              const int* __restrict__ dst,
                                              int* __restrict__ cursor,
                                              int* __restrict__ csr, int E) {
  int e = blockIdx.x * 256 + threadIdx.x;
  if (e < E) {
    int d = dst[e];
    int pos = atomicAdd(&cursor[d], 1);
    csr[pos] = src[e];
  }
}

// ---------------- W prep: fp32 [k][n] -> bf16 transposed [n][k] ----------------
__global__ __launch_bounds__(256) void k_prep_w(const float* __restrict__ W1,
                                                const float* __restrict__ W2,
                                                unsigned short* __restrict__ Wt1,
                                                unsigned short* __restrict__ Wt2) {
  const float* W = blockIdx.x ? W2 : W1;
  unsigned short* Wt = blockIdx.x ? Wt2 : Wt1;
  int tid = threadIdx.x;
#pragma unroll
  for (int i = 0; i < 64; i++) {
    int idx = tid + 256 * i;          // coalesced read
    int k = idx >> 7, n = idx & 127;
    Wt[n * 128 + k] = f2b(W[idx]);
  }
}

// ---------------- bf16 MFMA GEMM: out_bf16 = (relu? relu(in) : in) @ W ----------------
// block 256 = 4 waves; tile 64 rows x 128 cols; K=128 in one staged pass
__global__ __launch_bounds__(256) void k_gemm(const float* __restrict__ in,
                                              const unsigned short* __restrict__ Wt, // [n][k] bf16
                                              unsigned short* __restrict__ out,      // [m][n] bf16
                                              int n, int relu) {
  __shared__ short As[64 * AP];    // 17408 B : A[m][k] bf16
  __shared__ short Bs[128 * AP];   // 34816 B : W^T[n][k] bf16
  int tid = threadIdx.x;
  int wave = tid >> 6, lane = tid & 63;
  int quad = lane >> 4, l16 = lane & 15;
  int row0 = blockIdx.x * 64;

  // stage A: fp32 -> relu -> bf16
  const float4* in4 = (const float4*)in;
#pragma unroll
  for (int i = 0; i < 8; i++) {
    int idx = tid + 256 * i;          // 2048 float4 = 64 rows x 32
    int r = idx >> 5, c4 = idx & 31;
    int gr = row0 + r;
    float4 v = make_float4(0.f, 0.f, 0.f, 0.f);
    if (gr < n) {
      v = in4[(size_t)gr * 32 + c4];
      if (relu) {
        v.x = fmaxf(v.x, 0.f); v.y = fmaxf(v.y, 0.f);
        v.z = fmaxf(v.z, 0.f); v.w = fmaxf(v.w, 0.f);
      }
    }
    ushort4 w; w.x = f2b(v.x); w.y = f2b(v.y); w.z = f2b(v.z); w.w = f2b(v.w);
    *(ushort4*)&As[r * AP + c4 * 4] = w;
  }
  // stage B: copy bf16 W^T (16B chunks)
  const float4* Wt4 = (const float4*)Wt;   // 8 bf16 per float4
#pragma unroll
  for (int i = 0; i < 8; i++) {
    int idx = tid + 256 * i;          // 2048 chunks = 128 rows x 16
    int nr = idx >> 4, c = idx & 15;
    *(float4*)&Bs[nr * AP + c * 8] = Wt4[nr * 16 + c];
  }
  __syncthreads();

  // wave handles cols [wave*32, wave*32+32): 2 n-tiles; 4 m-tiles
  floatx4 acc[4][2];
#pragma unroll
  for (int mt = 0; mt < 4; mt++)
#pragma unroll
    for (int nt = 0; nt < 2; nt++) acc[mt][nt] = (floatx4)(0.f);

#pragma unroll
  for (int ks = 0; ks < 4; ks++) {
    short8 a[4], b[2];
#pragma unroll
    for (int mt = 0; mt < 4; mt++)
      a[mt] = *(const short8*)&As[(mt * 16 + l16) * AP + ks * 32 + quad * 8];
#pragma unroll
    for (int nt = 0; nt < 2; nt++)
      b[nt] = *(const short8*)&Bs[(wave * 32 + nt * 16 + l16) * AP + ks * 32 + quad * 8];
#pragma unroll
    for (int mt = 0; mt < 4; mt++)
#pragma unroll
      for (int nt = 0; nt < 2; nt++)
        acc[mt][nt] = __builtin_amdgcn_mfma_f32_16x16x32_bf16(a[mt], b[nt], acc[mt][nt], 0, 0, 0);
  }

  // epilogue: C/D layout col=lane&15, row=quad*4+r
#pragma unroll
  for (int mt = 0; mt < 4; mt++) {
#pragma unroll
    for (int nt = 0; nt < 2; nt++) {
#pragma unroll
      for (int r = 0; r < 4; r++) {
        int gr = row0 + mt * 16 + quad * 4 + r;
        if (gr < n)
          out[(size_t)gr * H + wave * 32 + nt * 16 + l16] = f2b(acc[mt][nt][r]);
      }
    }
  }
}

// ---------------- aggregation: one wave per node, bf16 h gathers ----------------
// out[i,:] = b + x[i,:] + dinv[i]^2 * h[i,:] + sum_e dinv[src]*dinv[i]*h[src,:]
__global__ __launch_bounds__(256) void k_agg(const unsigned int* __restrict__ h, // bf16x2 words
                                             const int* __restrict__ csr,
                                             const int* __restrict__ roff,
                                             const float* __restrict__ dinv,
                                             const float* __restrict__ bias,
                                             const float* __restrict__ x,
                                             float* __restrict__ out, int n) {
  int wave = threadIdx.x >> 6;
  int lane = threadIdx.x & 63;
  int node = blockIdx.x * 4 + wave;
  if (node >= n) return;

  float di = dinv[node];
  unsigned int su = h[(size_t)node * 64 + lane];
  float s0 = __uint_as_float(su << 16);
  float s1 = __uint_as_float(su & 0xffff0000u);
  float2 xv = ((const float2*)x)[(size_t)node * 64 + lane];
  float2 bv = ((const float2*)bias)[lane];
  float acc0 = bv.x + xv.x + di * di * s0;
  float acc1 = bv.y + xv.y + di * di * s1;

  int e0 = roff[node], e1 = roff[node + 1];
  int e = e0;
  for (; e + 4 <= e1; e += 4) {
    int i0 = csr[e], i1 = csr[e + 1], i2 = csr[e + 2], i3 = csr[e + 3];
    float c0 = di * dinv[i0], c1 = di * dinv[i1];
    float c2 = di * dinv[i2], c3 = di * dinv[i3];
    unsigned int u0 = h[(size_t)i0 * 64 + lane];
    unsigned int u1 = h[(size_t)i1 * 64 + lane];
    unsigned int u2 = h[(size_t)i2 * 64 + lane];
    unsigned int u3 = h[(size_t)i3 * 64 + lane];
    acc0 += c0 * __uint_as_float(u0 << 16) + c1 * __uint_as_float(u1 << 16);
    acc1 += c0 * __uint_as_float(u0 & 0xffff0000u) + c1 * __uint_as_float(u1 & 0xffff0000u);
    acc0 += c2 * __uint_as_float(u2 << 16) + c3 * __uint_as_float(u3 << 16);
    acc1 += c2 * __uint_as_float(u2 & 0xffff0000u) + c3 * __uint_as_float(u3 & 0xffff0000u);
  }
  for (; e < e1; e++) {
    int s = csr[e];
    float coef = di * dinv[s];
    unsigned int u = h[(size_t)s * 64 + lane];
    acc0 += coef * __uint_as_float(u << 16);
    acc1 += coef * __uint_as_float(u & 0xffff0000u);
  }
  ((float2*)out)[(size_t)node * 64 + lane] = make_float2(acc0, acc1);
}

extern "C" void kernel_launch(void* const* d_in, const int* in_sizes, int n_in,
                              void* d_out, int out_size, void* d_ws, size_t ws_size,
                              hipStream_t stream) {
  const float* x = (const float*)d_in[0];
  const int* src = (const int*)d_in[1];
  const int* dst = (const int*)d_in[2];
  const float* W1 = (const float*)d_in[3];
  const float* b1 = (const float*)d_in[4];
  const float* W2 = (const float*)d_in[5];
  const float* b2 = (const float*)d_in[6];
  int N = in_sizes[0] / H;
  int E = in_sizes[1];
  float* out = (float*)d_out;

  char* p = (char*)d_ws;
  auto alloc = [&](size_t bytes) {
    char* q = p;
    p += (bytes + 255) & ~(size_t)255;
    return q;
  };
  int* cnt = (int*)alloc((size_t)N * 4);
  int* roff = (int*)alloc((size_t)(N + 1) * 4);
  int* cursor = (int*)alloc((size_t)N * 4);
  float* dinv = (float*)alloc((size_t)N * 4);
  int* csr = (int*)alloc((size_t)E * 4);
  unsigned short* htmp = (unsigned short*)alloc((size_t)N * H * 2);  // bf16
  float* ybuf = (float*)alloc((size_t)N * H * 4);
  unsigned short* Wt1 = (unsigned short*)alloc(128 * 128 * 2);
  unsigned short* Wt2 = (unsigned short*)alloc(128 * 128 * 2);
  int* bsum = (int*)alloc(1024 * 4);
  int* boff = (int*)alloc(1024 * 4);

  int nb = (N + SCAN_BLK - 1) / SCAN_BLK;  // 98 for N=100000

  hipMemsetAsync(cnt, 0, (size_t)N * 4, stream);
  k_deg<<<(E + 255) / 256, 256, 0, stream>>>(dst, cnt, E);
  k_scan1<<<nb, 256, 0, stream>>>(cnt, bsum, N);
  k_scan2<<<1, 1024, 0, stream>>>(bsum, boff, roff, nb, N);
  k_scan3<<<nb, 256, 0, stream>>>(cnt, boff, roff, cursor, dinv, N);
  k_fill<<<(E + 255) / 256, 256, 0, stream>>>(src, dst, cursor, csr, E);
  k_prep_w<<<2, 256, 0, stream>>>(W1, W2, Wt1, Wt2);

  int gb = (N + 63) / 64;
  int ab = (N + 3) / 4;

  // layer 1
  k_gemm<<<gb, 256, 0, stream>>>(x, Wt1, htmp, N, 0);
  k_agg<<<ab, 256, 0, stream>>>((const unsigned int*)htmp, csr, roff, dinv, b1, x, ybuf, N);
  // layer 2
  k_gemm<<<gb, 256, 0, stream>>>(ybuf, Wt2, htmp, N, 1);
  k_agg<<<ab, 256, 0, stream>>>((const unsigned int*)htmp, csr, roff, dinv, b2, x, ybuf, N);
  // layer 3
  k_gemm<<<gb, 256, 0, stream>>>(ybuf, Wt2, htmp, N, 1);
  k_agg<<<ab, 256, 0, stream>>>((const unsigned int*)htmp, csr, roff, dinv, b2, x, out, N);
}

// Round 4
// 498.182 us; speedup vs baseline: 2.3022x; 1.2183x over previous
//
#include <hip/hip_runtime.h>

#define H 128
#define AP 136           // LDS row pitch in shorts
#define SCAN_BLK 1024

typedef __attribute__((ext_vector_type(8))) short short8;
typedef __attribute__((ext_vector_type(4))) float floatx4;

__device__ inline unsigned short f2b(float f) {   // fp32 -> bf16 RNE
  union { float f; unsigned u; } v; v.f = f;
  unsigned r = v.u + 0x7fffu + ((v.u >> 16) & 1u);
  return (unsigned short)(r >> 16);
}

// ---------------- degree histogram + edge rank ----------------
__global__ __launch_bounds__(256) void k_deg(const int* __restrict__ dst,
                                             int* __restrict__ cnt,
                                             int* __restrict__ rank, int E) {
  int e = blockIdx.x * 256 + threadIdx.x;
  if (e < E) rank[e] = atomicAdd(&cnt[dst[e]], 1);
}

// ---------------- hierarchical scan ----------------
__global__ __launch_bounds__(256) void k_scan1(const int* __restrict__ cnt,
                                               int* __restrict__ bsum, int n) {
  __shared__ int red[256];
  int tid = threadIdx.x;
  int i0 = blockIdx.x * SCAN_BLK + tid * 4;
  int s = 0;
#pragma unroll
  for (int j = 0; j < 4; j++) { int i = i0 + j; if (i < n) s += cnt[i]; }
  red[tid] = s;
  __syncthreads();
  for (int off = 128; off > 0; off >>= 1) {
    if (tid < off) red[tid] += red[tid + off];
    __syncthreads();
  }
  if (tid == 0) bsum[blockIdx.x] = red[0];
}

__global__ __launch_bounds__(1024) void k_scan2(const int* __restrict__ bsum,
                                                int* __restrict__ boff,
                                                int* __restrict__ roff,
                                                int nb, int n) {
  __shared__ int sums[1024];
  int tid = threadIdx.x;
  int v = (tid < nb) ? bsum[tid] : 0;
  sums[tid] = v;
  __syncthreads();
  for (int off = 1; off < 1024; off <<= 1) {
    int t = (tid >= off) ? sums[tid - off] : 0;
    __syncthreads();
    sums[tid] += t;
    __syncthreads();
  }
  if (tid < nb) boff[tid] = sums[tid] - v;
  if (tid == 1023) roff[n] = sums[1023];
}

__global__ __launch_bounds__(256) void k_scan3(const int* __restrict__ cnt,
                                               const int* __restrict__ boff,
                                               int* __restrict__ roff,
                                               float* __restrict__ dinv, int n) {
  __shared__ int sums[256];
  int tid = threadIdx.x;
  int i0 = blockIdx.x * SCAN_BLK + tid * 4;
  int local[4];
  int s = 0;
#pragma unroll
  for (int j = 0; j < 4; j++) {
    int i = i0 + j;
    int v = (i < n) ? cnt[i] : 0;
    local[j] = s;
    s += v;
    if (i < n) dinv[i] = rsqrtf((float)v + 1.0f);
  }
  sums[tid] = s;
  __syncthreads();
  for (int off = 1; off < 256; off <<= 1) {
    int t = (tid >= off) ? sums[tid - off] : 0;
    __syncthreads();
    sums[tid] += t;
    __syncthreads();
  }
  int base = boff[blockIdx.x] + sums[tid] - s;
#pragma unroll
  for (int j = 0; j < 4; j++) {
    int i = i0 + j;
    if (i < n) roff[i] = base + local[j];
  }
}

// ---------------- CSR fill (atomic-free: pos = roff[dst] + rank) ----------------
__global__ __launch_bounds__(256) void k_fill(const int* __restrict__ src,
                                              const int* __restrict__ dst,
                                              const int* __restrict__ rank,
                                              const int* __restrict__ roff,
                                              int* __restrict__ csr, int E) {
  int e = blockIdx.x * 256 + threadIdx.x;
  if (e < E) {
    int pos = roff[dst[e]] + rank[e];
    csr[pos] = src[e];
  }
}

// ---------------- W prep: fp32 [k][n] -> bf16 transposed [n][k] ----------------
__global__ __launch_bounds__(256) void k_prep_w(const float* __restrict__ W1,
                                                const float* __restrict__ W2,
                                                unsigned short* __restrict__ Wt1,
                                                unsigned short* __restrict__ Wt2) {
  const float* W = blockIdx.x ? W2 : W1;
  unsigned short* Wt = blockIdx.x ? Wt2 : Wt1;
  int tid = threadIdx.x;
#pragma unroll
  for (int i = 0; i < 64; i++) {
    int idx = tid + 256 * i;
    int k = idx >> 7, n = idx & 127;
    Wt[n * 128 + k] = f2b(W[idx]);
  }
}

// ---------------- bf16 MFMA GEMM: out_bf16 = in @ W ----------------
// in is fp32 (in_bf16=0) or bf16 (in_bf16=1, already relu'd upstream)
__global__ __launch_bounds__(256) void k_gemm(const void* __restrict__ in,
                                              const unsigned short* __restrict__ Wt, // [n][k] bf16
                                              unsigned short* __restrict__ out,      // [m][n] bf16
                                              int n, int in_bf16) {
  __shared__ short As[64 * AP];
  __shared__ short Bs[128 * AP];
  int tid = threadIdx.x;
  int wave = tid >> 6, lane = tid & 63;
  int quad = lane >> 4, l16 = lane & 15;
  int row0 = blockIdx.x * 64;

  if (in_bf16) {
    // direct bf16 copy: 64 rows x 128 shorts = 1024 16B-chunks
    const float4* in4 = (const float4*)in;
#pragma unroll
    for (int i = 0; i < 4; i++) {
      int idx = tid + 256 * i;
      int r = idx >> 4, c = idx & 15;     // 16 chunks per row
      int gr = row0 + r;
      float4 v = make_float4(0.f, 0.f, 0.f, 0.f);
      if (gr < n) v = in4[(size_t)gr * 16 + c];
      *(float4*)&As[r * AP + c * 8] = v;
    }
  } else {
    const float4* in4 = (const float4*)in;
#pragma unroll
    for (int i = 0; i < 8; i++) {
      int idx = tid + 256 * i;            // 2048 float4 = 64 rows x 32
      int r = idx >> 5, c4 = idx & 31;
      int gr = row0 + r;
      float4 v = make_float4(0.f, 0.f, 0.f, 0.f);
      if (gr < n) v = in4[(size_t)gr * 32 + c4];
      ushort4 w; w.x = f2b(v.x); w.y = f2b(v.y); w.z = f2b(v.z); w.w = f2b(v.w);
      *(ushort4*)&As[r * AP + c4 * 4] = w;
    }
  }
  // stage B
  const float4* Wt4 = (const float4*)Wt;
#pragma unroll
  for (int i = 0; i < 8; i++) {
    int idx = tid + 256 * i;
    int nr = idx >> 4, c = idx & 15;
    *(float4*)&Bs[nr * AP + c * 8] = Wt4[nr * 16 + c];
  }
  __syncthreads();

  floatx4 acc[4][2];
#pragma unroll
  for (int mt = 0; mt < 4; mt++)
#pragma unroll
    for (int nt = 0; nt < 2; nt++) acc[mt][nt] = (floatx4)(0.f);

#pragma unroll
  for (int ks = 0; ks < 4; ks++) {
    short8 a[4], b[2];
#pragma unroll
    for (int mt = 0; mt < 4; mt++)
      a[mt] = *(const short8*)&As[(mt * 16 + l16) * AP + ks * 32 + quad * 8];
#pragma unroll
    for (int nt = 0; nt < 2; nt++)
      b[nt] = *(const short8*)&Bs[(wave * 32 + nt * 16 + l16) * AP + ks * 32 + quad * 8];
#pragma unroll
    for (int mt = 0; mt < 4; mt++)
#pragma unroll
      for (int nt = 0; nt < 2; nt++)
        acc[mt][nt] = __builtin_amdgcn_mfma_f32_16x16x32_bf16(a[mt], b[nt], acc[mt][nt], 0, 0, 0);
  }

#pragma unroll
  for (int mt = 0; mt < 4; mt++) {
#pragma unroll
    for (int nt = 0; nt < 2; nt++) {
#pragma unroll
      for (int r = 0; r < 4; r++) {
        int gr = row0 + mt * 16 + quad * 4 + r;
        if (gr < n)
          out[(size_t)gr * H + wave * 32 + nt * 16 + l16] = f2b(acc[mt][nt][r]);
      }
    }
  }
}

// ---------------- aggregation: one wave per node, bf16 h gathers ----------------
// y[i,:] = b + x[i,:] + dinv[i]^2 * h[i,:] + sum_e dinv[src]*dinv[i]*h[src,:]
// write16=1: out16[i,:] = bf16(relu(y))   (layers 1,2 -> next gemm input)
// write16=0: out32[i,:] = y               (layer 3 -> d_out)
__global__ __launch_bounds__(256) void k_agg(const unsigned int* __restrict__ h, // bf16x2 words
                                             const int* __restrict__ csr,
                                             const int* __restrict__ roff,
                                             const float* __restrict__ dinv,
                                             const float* __restrict__ bias,
                                             const float* __restrict__ x,
                                             float* __restrict__ out32,
                                             unsigned int* __restrict__ out16,
                                             int n, int write16) {
  int wave = threadIdx.x >> 6;
  int lane = threadIdx.x & 63;
  int node = blockIdx.x * 4 + wave;
  if (node >= n) return;

  float di = dinv[node];
  unsigned int su = h[(size_t)node * 64 + lane];
  float s0 = __uint_as_float(su << 16);
  float s1 = __uint_as_float(su & 0xffff0000u);
  float2 xv = ((const float2*)x)[(size_t)node * 64 + lane];
  float2 bv = ((const float2*)bias)[lane];
  float acc0 = bv.x + xv.x + di * di * s0;
  float acc1 = bv.y + xv.y + di * di * s1;

  int e0 = roff[node], e1 = roff[node + 1];
  int e = e0;
  for (; e + 4 <= e1; e += 4) {
    int i0 = csr[e], i1 = csr[e + 1], i2 = csr[e + 2], i3 = csr[e + 3];
    float c0 = di * dinv[i0], c1 = di * dinv[i1];
    float c2 = di * dinv[i2], c3 = di * dinv[i3];
    unsigned int u0 = h[(size_t)i0 * 64 + lane];
    unsigned int u1 = h[(size_t)i1 * 64 + lane];
    unsigned int u2 = h[(size_t)i2 * 64 + lane];
    unsigned int u3 = h[(size_t)i3 * 64 + lane];
    acc0 += c0 * __uint_as_float(u0 << 16) + c1 * __uint_as_float(u1 << 16);
    acc1 += c0 * __uint_as_float(u0 & 0xffff0000u) + c1 * __uint_as_float(u1 & 0xffff0000u);
    acc0 += c2 * __uint_as_float(u2 << 16) + c3 * __uint_as_float(u3 << 16);
    acc1 += c2 * __uint_as_float(u2 & 0xffff0000u) + c3 * __uint_as_float(u3 & 0xffff0000u);
  }
  for (; e < e1; e++) {
    int s = csr[e];
    float coef = di * dinv[s];
    unsigned int u = h[(size_t)s * 64 + lane];
    acc0 += coef * __uint_as_float(u << 16);
    acc1 += coef * __uint_as_float(u & 0xffff0000u);
  }
  if (write16) {
    float r0 = fmaxf(acc0, 0.f), r1 = fmaxf(acc1, 0.f);
    out16[(size_t)node * 64 + lane] = (unsigned int)f2b(r0) | ((unsigned int)f2b(r1) << 16);
  } else {
    ((float2*)out32)[(size_t)node * 64 + lane] = make_float2(acc0, acc1);
  }
}

extern "C" void kernel_launch(void* const* d_in, const int* in_sizes, int n_in,
                              void* d_out, int out_size, void* d_ws, size_t ws_size,
                              hipStream_t stream) {
  const float* x = (const float*)d_in[0];
  const int* src = (const int*)d_in[1];
  const int* dst = (const int*)d_in[2];
  const float* W1 = (const float*)d_in[3];
  const float* b1 = (const float*)d_in[4];
  const float* W2 = (const float*)d_in[5];
  const float* b2 = (const float*)d_in[6];
  int N = in_sizes[0] / H;
  int E = in_sizes[1];
  float* out = (float*)d_out;

  char* p = (char*)d_ws;
  auto alloc = [&](size_t bytes) {
    char* q = p;
    p += (bytes + 255) & ~(size_t)255;
    return q;
  };
  int* cnt = (int*)alloc((size_t)N * 4);
  int* roff = (int*)alloc((size_t)(N + 1) * 4);
  float* dinv = (float*)alloc((size_t)N * 4);
  int* rank = (int*)alloc((size_t)E * 4);
  int* csr = (int*)alloc((size_t)E * 4);
  unsigned short* htmp = (unsigned short*)alloc((size_t)N * H * 2);   // bf16 h
  unsigned int* ybuf16 = (unsigned int*)alloc((size_t)N * H * 2);     // bf16 relu(y)
  unsigned short* Wt1 = (unsigned short*)alloc(128 * 128 * 2);
  unsigned short* Wt2 = (unsigned short*)alloc(128 * 128 * 2);
  int* bsum = (int*)alloc(1024 * 4);
  int* boff = (int*)alloc(1024 * 4);

  int nb = (N + SCAN_BLK - 1) / SCAN_BLK;  // 98 for N=100000

  hipMemsetAsync(cnt, 0, (size_t)N * 4, stream);
  k_deg<<<(E + 255) / 256, 256, 0, stream>>>(dst, cnt, rank, E);
  k_scan1<<<nb, 256, 0, stream>>>(cnt, bsum, N);
  k_scan2<<<1, 1024, 0, stream>>>(bsum, boff, roff, nb, N);
  k_scan3<<<nb, 256, 0, stream>>>(cnt, boff, roff, dinv, N);
  k_fill<<<(E + 255) / 256, 256, 0, stream>>>(src, dst, rank, roff, csr, E);
  k_prep_w<<<2, 256, 0, stream>>>(W1, W2, Wt1, Wt2);

  int gb = (N + 63) / 64;
  int ab = (N + 3) / 4;

  // layer 1: x(fp32) @ W1 -> agg -> relu'd bf16 y1
  k_gemm<<<gb, 256, 0, stream>>>(x, Wt1, htmp, N, 0);
  k_agg<<<ab, 256, 0, stream>>>((const unsigned int*)htmp, csr, roff, dinv, b1, x, nullptr, ybuf16, N, 1);
  // layer 2: y1(bf16) @ W2 -> agg -> relu'd bf16 y2
  k_gemm<<<gb, 256, 0, stream>>>(ybuf16, Wt2, htmp, N, 1);
  k_agg<<<ab, 256, 0, stream>>>((const unsigned int*)htmp, csr, roff, dinv, b2, x, nullptr, ybuf16, N, 1);
  // layer 3: y2(bf16) @ W2 -> agg -> fp32 out
  k_gemm<<<gb, 256, 0, stream>>>(ybuf16, Wt2, htmp, N, 1);
  k_agg<<<ab, 256, 0, stream>>>((const unsigned int*)htmp, csr, roff, dinv, b2, x, out, nullptr, N, 0);
}